// Round 1
// baseline (461.754 us; speedup 1.0000x reference)
//
#include <hip/hip_runtime.h>
#include <hip/hip_bf16.h>

#define N_NODES 50000
#define N_EDGES 800000

constexpr int NP = 50176;  // N_NODES padded to 256

// ---------------- CSR build ----------------
__global__ void count_kernel(const int* __restrict__ dst, int* __restrict__ cnt, int E) {
    int i = blockIdx.x * blockDim.x + threadIdx.x;
    if (i < E) atomicAdd(&cnt[dst[i]], 1);
}

__global__ void scan_kernel(const int* __restrict__ cnt, int* __restrict__ row_ptr,
                            float* __restrict__ inv_deg, int n) {
    __shared__ int wsum[16];
    int tid = threadIdx.x;
    int lane = tid & 63;
    int w = tid >> 6;
    int carry = 0;
    for (int base = 0; base < n; base += 1024) {
        int i = base + tid;
        int v = (i < n) ? cnt[i] : 0;
        int s = v;
        #pragma unroll
        for (int off = 1; off < 64; off <<= 1) {
            int t = __shfl_up(s, off);
            if (lane >= off) s += t;
        }
        if (lane == 63) wsum[w] = s;
        __syncthreads();
        if (w == 0 && lane < 16) {
            int ws_ = wsum[lane];
            #pragma unroll
            for (int off = 1; off < 16; off <<= 1) {
                int t = __shfl_up(ws_, off);
                if (lane >= off) ws_ += t;
            }
            wsum[lane] = ws_;
        }
        __syncthreads();
        int woff = (w == 0) ? 0 : wsum[w - 1];
        int excl = carry + woff + (s - v);
        if (i < n) {
            row_ptr[i] = excl;
            inv_deg[i] = 1.0f / (float)(v > 1 ? v : 1);
        }
        int tot = wsum[15];
        __syncthreads();
        carry += tot;
    }
    if (tid == 0) row_ptr[n] = carry;
}

__global__ void fill_kernel(const int* __restrict__ src, const int* __restrict__ dst,
                            const int* __restrict__ row_ptr, int* __restrict__ cursor,
                            int* __restrict__ edge_src, int E) {
    int i = blockIdx.x * blockDim.x + threadIdx.x;
    if (i < E) {
        int d = dst[i];
        int p = atomicAdd(&cursor[d], 1);
        edge_src[row_ptr[d] + p] = src[i];
    }
}

// Bt[k][j] = (k < din) ? Wl[j][k] : Wr[j][k-din]   (K = 2*din rows, dout cols)
__global__ void build_bt_kernel(const float* __restrict__ Wl, const float* __restrict__ Wr,
                                float* __restrict__ Bt, int din, int dout) {
    int idx = blockIdx.x * blockDim.x + threadIdx.x;
    int tot = 2 * din * dout;
    if (idx >= tot) return;
    int k = idx / dout;
    int j = idx - k * dout;
    Bt[idx] = (k < din) ? Wl[j * din + k] : Wr[j * din + (k - din)];
}

// ---------------- mean aggregation: one wave per node ----------------
template<int D>
__global__ __launch_bounds__(256) void agg_kernel(
        const float* __restrict__ h, int hstride,
        const int* __restrict__ row_ptr, const int* __restrict__ edge_src,
        const float* __restrict__ inv_deg, float* __restrict__ mean, int n) {
    int wid = (blockIdx.x * 256 + threadIdx.x) >> 6;
    int lane = threadIdx.x & 63;
    if (wid >= n) return;
    int beg = row_ptr[wid];
    int end = row_ptr[wid + 1];
    float inv = inv_deg[wid];
    if constexpr (D == 128) {
        float ax = 0.f, ay = 0.f;
        int e = beg;
        for (; e + 2 <= end; e += 2) {
            int s0 = edge_src[e];
            int s1 = edge_src[e + 1];
            float2 v0 = *reinterpret_cast<const float2*>(h + (long)s0 * hstride + lane * 2);
            float2 v1 = *reinterpret_cast<const float2*>(h + (long)s1 * hstride + lane * 2);
            ax += v0.x + v1.x;
            ay += v0.y + v1.y;
        }
        if (e < end) {
            int s0 = edge_src[e];
            float2 v0 = *reinterpret_cast<const float2*>(h + (long)s0 * hstride + lane * 2);
            ax += v0.x;
            ay += v0.y;
        }
        float2 r;
        r.x = ax * inv;
        r.y = ay * inv;
        *reinterpret_cast<float2*>(mean + (long)wid * 128 + lane * 2) = r;
    } else {
        float a = 0.f;
        for (int e = beg; e < end; ++e) {
            int s0 = edge_src[e];
            a += h[(long)s0 * hstride + lane];
        }
        mean[(long)wid * 64 + lane] = a * inv;
    }
}

// ---------------- fused GEMM: out = relu([A1|A2] @ Bt + bias) ----------------
// A1 = mean (n x K/2, stride a1s), A2 = prev features (n x K/2, stride a2s)
// Bt = (K x DOUT), out strided (concat layout)
template<int K, int DOUT>
__global__ __launch_bounds__(256) void gemm_kernel(
        const float* __restrict__ A1, int a1s,
        const float* __restrict__ A2, int a2s,
        const float* __restrict__ Bt, const float* __restrict__ bias,
        float* __restrict__ out, int outs, int n) {
    constexpr int BM = 64, BK = 64;
    constexpr int DIN = K / 2;
    constexpr int NN = DOUT / 16;       // 8 or 4 outputs per thread-col
    constexpr int ASTR = BK + 1;        // 65: conflict-free column reads
    constexpr int BSTR = DOUT + 4;
    __shared__ float A_l[BM * ASTR];
    __shared__ float B_l[BK * BSTR];
    int tid = threadIdx.x;
    int tm = tid >> 4;
    int tn = tid & 15;
    int n0 = blockIdx.x * BM;
    float acc[4][NN];
    #pragma unroll
    for (int i = 0; i < 4; ++i)
        #pragma unroll
        for (int j = 0; j < NN; ++j) acc[i][j] = 0.f;

    for (int kt = 0; kt < K / BK; ++kt) {
        int kb = kt * BK;
        const float* srcp;
        int rs;
        if (kb < DIN) { srcp = A1 + (long)n0 * a1s + kb; rs = a1s; }
        else          { srcp = A2 + (long)n0 * a2s + (kb - DIN); rs = a2s; }
        // stage A: 64 x 64 floats
        #pragma unroll
        for (int i = 0; i < 4; ++i) {
            int flat = tid + i * 256;
            int row = flat >> 4;
            int c4 = (flat & 15) << 2;
            int gn = n0 + row;
            float4 v = {0.f, 0.f, 0.f, 0.f};
            if (gn < n) v = *reinterpret_cast<const float4*>(srcp + (long)row * rs + c4);
            float* p = &A_l[row * ASTR + c4];
            p[0] = v.x; p[1] = v.y; p[2] = v.z; p[3] = v.w;
        }
        // stage B: 64 x DOUT floats
        constexpr int BITER = BK * DOUT / 4 / 256;
        #pragma unroll
        for (int i = 0; i < BITER; ++i) {
            int flat = tid + i * 256;
            int row = flat / (DOUT / 4);
            int c4 = (flat % (DOUT / 4)) << 2;
            float4 v = *reinterpret_cast<const float4*>(Bt + (long)(kb + row) * DOUT + c4);
            *reinterpret_cast<float4*>(&B_l[row * BSTR + c4]) = v;
        }
        __syncthreads();
        #pragma unroll 4
        for (int k = 0; k < BK; ++k) {
            float a0 = A_l[(tm * 4 + 0) * ASTR + k];
            float a1 = A_l[(tm * 4 + 1) * ASTR + k];
            float a2 = A_l[(tm * 4 + 2) * ASTR + k];
            float a3 = A_l[(tm * 4 + 3) * ASTR + k];
            float bv[NN];
            #pragma unroll
            for (int j = 0; j < NN; ++j) bv[j] = B_l[k * BSTR + tn * NN + j];
            #pragma unroll
            for (int j = 0; j < NN; ++j) {
                acc[0][j] = fmaf(a0, bv[j], acc[0][j]);
                acc[1][j] = fmaf(a1, bv[j], acc[1][j]);
                acc[2][j] = fmaf(a2, bv[j], acc[2][j]);
                acc[3][j] = fmaf(a3, bv[j], acc[3][j]);
            }
        }
        __syncthreads();
    }
    #pragma unroll
    for (int mm = 0; mm < 4; ++mm) {
        int gn = n0 + tm * 4 + mm;
        if (gn < n) {
            #pragma unroll
            for (int j = 0; j < NN; ++j) {
                float v = acc[mm][j] + bias[tn * NN + j];
                out[(long)gn * outs + tn * NN + j] = fmaxf(v, 0.f);
            }
        }
    }
}

extern "C" void kernel_launch(void* const* d_in, const int* in_sizes, int n_in,
                              void* d_out, int out_size, void* d_ws, size_t ws_size,
                              hipStream_t stream) {
    const float* x   = (const float*)d_in[0];
    const int*   ei  = (const int*)d_in[1];
    const float* W1l = (const float*)d_in[2];
    const float* b1  = (const float*)d_in[3];
    const float* W1r = (const float*)d_in[4];
    const float* W2l = (const float*)d_in[5];
    const float* b2  = (const float*)d_in[6];
    const float* W2r = (const float*)d_in[7];
    const float* W3l = (const float*)d_in[8];
    const float* b3  = (const float*)d_in[9];
    const float* W3r = (const float*)d_in[10];
    float* out = (float*)d_out;

    const int* src = ei;             // edge_index[0]
    const int* dst = ei + N_EDGES;   // edge_index[1]

    char* ws = (char*)d_ws;
    int*   cnt      = (int*)ws;                                   // NP ints
    int*   cursor   = (int*)(ws + (size_t)NP * 4);                // NP ints
    int*   row_ptr  = (int*)(ws + (size_t)2 * NP * 4);            // N+1 ints
    float* inv_deg  = (float*)(ws + (size_t)3 * NP * 4);          // N floats
    int*   edge_src = (int*)(ws + (size_t)4 * NP * 4);            // E ints
    float* Bt1 = (float*)(ws + (size_t)4 * NP * 4 + (size_t)N_EDGES * 4);
    float* Bt2 = Bt1 + 256 * 128;
    float* Bt3 = Bt2 + 256 * 64;
    float* mean = Bt3 + 128 * 128;                                // N*128 floats

    // zero degree counters + cursors (contiguous)
    hipMemsetAsync(cnt, 0, (size_t)2 * NP * 4, stream);

    const int EB = (N_EDGES + 255) / 256;
    count_kernel<<<EB, 256, 0, stream>>>(dst, cnt, N_EDGES);
    scan_kernel<<<1, 1024, 0, stream>>>(cnt, row_ptr, inv_deg, N_NODES);
    fill_kernel<<<EB, 256, 0, stream>>>(src, dst, row_ptr, cursor, edge_src, N_EDGES);

    build_bt_kernel<<<(2 * 128 * 128 + 255) / 256, 256, 0, stream>>>(W1l, W1r, Bt1, 128, 128);
    build_bt_kernel<<<(2 * 128 * 64 + 255) / 256, 256, 0, stream>>>(W2l, W2r, Bt2, 128, 64);
    build_bt_kernel<<<(2 * 64 * 128 + 255) / 256, 256, 0, stream>>>(W3l, W3r, Bt3, 64, 128);

    const int AGG_BLOCKS = (N_NODES + 3) / 4;       // 4 waves (nodes) per block
    const int GEMM_BLOCKS = (N_NODES + 63) / 64;

    // ---- layer 1: in = x (stride 128), out cols [0,128) ----
    agg_kernel<128><<<AGG_BLOCKS, 256, 0, stream>>>(x, 128, row_ptr, edge_src, inv_deg, mean, N_NODES);
    gemm_kernel<256, 128><<<GEMM_BLOCKS, 256, 0, stream>>>(mean, 128, x, 128, Bt1, b1, out + 0, 320, N_NODES);

    // ---- layer 2: in = h1 (out cols 0..127, stride 320), out cols [128,192) ----
    agg_kernel<128><<<AGG_BLOCKS, 256, 0, stream>>>(out, 320, row_ptr, edge_src, inv_deg, mean, N_NODES);
    gemm_kernel<256, 64><<<GEMM_BLOCKS, 256, 0, stream>>>(mean, 128, out, 320, Bt2, b2, out + 128, 320, N_NODES);

    // ---- layer 3: in = h2 (out cols 128..191, stride 320), out cols [192,320) ----
    agg_kernel<64><<<AGG_BLOCKS, 256, 0, stream>>>(out + 128, 320, row_ptr, edge_src, inv_deg, mean, N_NODES);
    gemm_kernel<128, 128><<<GEMM_BLOCKS, 256, 0, stream>>>(mean, 64, out + 128, 320, Bt3, b3, out + 192, 320, N_NODES);
}

// Round 2
// 330.041 us; speedup vs baseline: 1.3991x; 1.3991x over previous
//
#include <hip/hip_runtime.h>
#include <hip/hip_bf16.h>

#define N_NODES 50000
#define N_EDGES 800000

constexpr int NP = 50176;  // N_NODES padded to 256

__device__ __forceinline__ unsigned short f2bf(float f) {
    unsigned u = __float_as_uint(f);
    u += 0x7FFFu + ((u >> 16) & 1u);   // round-nearest-even
    return (unsigned short)(u >> 16);
}

// ---------------- CSR build ----------------
__global__ void count_kernel(const int* __restrict__ dst, int* __restrict__ cnt, int E) {
    int i = blockIdx.x * blockDim.x + threadIdx.x;
    if (i < E) atomicAdd(&cnt[dst[i]], 1);
}

// wave-scan + one atomic per wave assigns row offsets (order nondeterministic,
// but per-node edge sets -- and thus sums -- are unchanged)
__global__ void assign_kernel(const int* __restrict__ cnt, int* __restrict__ row_ptr,
                              float* __restrict__ inv_deg, int* __restrict__ total, int n) {
    int i = blockIdx.x * blockDim.x + threadIdx.x;
    int lane = threadIdx.x & 63;
    int v = (i < n) ? cnt[i] : 0;
    int s = v;
    #pragma unroll
    for (int off = 1; off < 64; off <<= 1) {
        int t = __shfl_up(s, off);
        if (lane >= off) s += t;
    }
    int base = 0;
    if (lane == 63) base = atomicAdd(total, s);
    base = __shfl(base, 63);
    if (i < n) {
        row_ptr[i] = base + s - v;
        inv_deg[i] = 1.0f / (float)(v > 1 ? v : 1);
    }
}

__global__ void fill_kernel(const int* __restrict__ src, const int* __restrict__ dst,
                            const int* __restrict__ row_ptr, int* __restrict__ cursor,
                            int* __restrict__ edge_src, int E) {
    int i = blockIdx.x * blockDim.x + threadIdx.x;
    if (i < E) {
        int d = dst[i];
        int p = atomicAdd(&cursor[d], 1);
        edge_src[row_ptr[d] + p] = src[i];
    }
}

// Bt[k][j] = (k < din) ? Wl[j][k] : Wr[j][k-din]
__global__ void build_bt_kernel(const float* __restrict__ Wl, const float* __restrict__ Wr,
                                float* __restrict__ Bt, int din, int dout) {
    int idx = blockIdx.x * blockDim.x + threadIdx.x;
    int tot = 2 * din * dout;
    if (idx >= tot) return;
    int k = idx / dout;
    int j = idx - k * dout;
    Bt[idx] = (k < din) ? Wl[j * din + k] : Wr[j * din + (k - din)];
}

// x (f32, dense 128) -> bf16 dense
__global__ void cvt_kernel(const float* __restrict__ src, unsigned short* __restrict__ dstb, int total4) {
    int i = blockIdx.x * blockDim.x + threadIdx.x;
    if (i >= total4) return;
    float4 v = reinterpret_cast<const float4*>(src)[i];
    uint2 p;
    p.x = (unsigned)f2bf(v.x) | ((unsigned)f2bf(v.y) << 16);
    p.y = (unsigned)f2bf(v.z) | ((unsigned)f2bf(v.w) << 16);
    reinterpret_cast<uint2*>(dstb)[i] = p;
}

// ---------------- mean aggregation: one wave per node, bf16 gather ----------------
// D/8 lanes cover one row with 16B loads; 64/(D/8) edges processed concurrently, x2 unroll.
template<int D>
__global__ __launch_bounds__(256) void agg_kernel(
        const unsigned short* __restrict__ hb,     // dense bf16 [n][D]
        const int* __restrict__ row_ptr, const int* __restrict__ cnt,
        const int* __restrict__ edge_src,
        const float* __restrict__ inv_deg, float* __restrict__ mean, int n) {
    constexpr int LPR = D / 8;      // lanes per row
    constexpr int EPW = 64 / LPR;   // edges in parallel per wave
    int wid = (blockIdx.x * 256 + threadIdx.x) >> 6;
    int lane = threadIdx.x & 63;
    if (wid >= n) return;
    int beg = row_ptr[wid];
    int end = beg + cnt[wid];
    float inv = inv_deg[wid];
    int sub = lane / LPR;
    int li = lane % LPR;

    float acc[8];
    #pragma unroll
    for (int j = 0; j < 8; ++j) acc[j] = 0.f;

    for (int e0 = beg; e0 < end; e0 += 2 * EPW) {
        int e = e0 + sub;
        int e2 = e + EPW;
        uint4 v0 = {0u, 0u, 0u, 0u}, v1 = {0u, 0u, 0u, 0u};
        if (e < end) {
            int s0 = edge_src[e];
            v0 = *reinterpret_cast<const uint4*>(hb + (size_t)s0 * D + li * 8);
        }
        if (e2 < end) {
            int s1 = edge_src[e2];
            v1 = *reinterpret_cast<const uint4*>(hb + (size_t)s1 * D + li * 8);
        }
        unsigned w;
        #define ACCW(u, j0) w = (u); acc[j0] += __uint_as_float(w << 16); acc[j0+1] += __uint_as_float(w & 0xFFFF0000u)
        ACCW(v0.x, 0); ACCW(v0.y, 2); ACCW(v0.z, 4); ACCW(v0.w, 6);
        ACCW(v1.x, 0); ACCW(v1.y, 2); ACCW(v1.z, 4); ACCW(v1.w, 6);
        #undef ACCW
    }
    // combine across the EPW sub-groups
    #pragma unroll
    for (int off = LPR; off < 64; off <<= 1) {
        #pragma unroll
        for (int j = 0; j < 8; ++j) acc[j] += __shfl_xor(acc[j], off);
    }
    if (lane < LPR) {
        float* mp = mean + (size_t)wid * D + li * 8;
        float4 r0 = {acc[0] * inv, acc[1] * inv, acc[2] * inv, acc[3] * inv};
        float4 r1 = {acc[4] * inv, acc[5] * inv, acc[6] * inv, acc[7] * inv};
        reinterpret_cast<float4*>(mp)[0] = r0;
        reinterpret_cast<float4*>(mp)[1] = r1;
    }
}

// ---------------- fused GEMM: out = relu([A1|A2] @ Bt + bias) ----------------
// optionally also writes dense bf16 copy (next layer's gather operand)
template<int K, int DOUT, bool WB>
__global__ __launch_bounds__(256) void gemm_kernel(
        const float* __restrict__ A1, int a1s,
        const float* __restrict__ A2, int a2s,
        const float* __restrict__ Bt, const float* __restrict__ bias,
        float* __restrict__ out, int outs,
        unsigned short* __restrict__ outb, int n) {
    constexpr int BM = 64, BK = 64;
    constexpr int DIN = K / 2;
    constexpr int NN = DOUT / 16;
    constexpr int ASTR = BK + 1;
    constexpr int BSTR = DOUT + 4;
    __shared__ float A_l[BM * ASTR];
    __shared__ float B_l[BK * BSTR];
    int tid = threadIdx.x;
    int tm = tid >> 4;
    int tn = tid & 15;
    int n0 = blockIdx.x * BM;
    float acc[4][NN];
    #pragma unroll
    for (int i = 0; i < 4; ++i)
        #pragma unroll
        for (int j = 0; j < NN; ++j) acc[i][j] = 0.f;

    for (int kt = 0; kt < K / BK; ++kt) {
        int kb = kt * BK;
        const float* srcp;
        int rs;
        if (kb < DIN) { srcp = A1 + (long)n0 * a1s + kb; rs = a1s; }
        else          { srcp = A2 + (long)n0 * a2s + (kb - DIN); rs = a2s; }
        #pragma unroll
        for (int i = 0; i < 4; ++i) {
            int flat = tid + i * 256;
            int row = flat >> 4;
            int c4 = (flat & 15) << 2;
            int gn = n0 + row;
            float4 v = {0.f, 0.f, 0.f, 0.f};
            if (gn < n) v = *reinterpret_cast<const float4*>(srcp + (long)row * rs + c4);
            float* p = &A_l[row * ASTR + c4];
            p[0] = v.x; p[1] = v.y; p[2] = v.z; p[3] = v.w;
        }
        constexpr int BITER = BK * DOUT / 4 / 256;
        #pragma unroll
        for (int i = 0; i < BITER; ++i) {
            int flat = tid + i * 256;
            int row = flat / (DOUT / 4);
            int c4 = (flat % (DOUT / 4)) << 2;
            float4 v = *reinterpret_cast<const float4*>(Bt + (long)(kb + row) * DOUT + c4);
            *reinterpret_cast<float4*>(&B_l[row * BSTR + c4]) = v;
        }
        __syncthreads();
        #pragma unroll 4
        for (int k = 0; k < BK; ++k) {
            float a0 = A_l[(tm * 4 + 0) * ASTR + k];
            float a1 = A_l[(tm * 4 + 1) * ASTR + k];
            float a2 = A_l[(tm * 4 + 2) * ASTR + k];
            float a3 = A_l[(tm * 4 + 3) * ASTR + k];
            float bv[NN];
            #pragma unroll
            for (int j = 0; j < NN; ++j) bv[j] = B_l[k * BSTR + tn * NN + j];
            #pragma unroll
            for (int j = 0; j < NN; ++j) {
                acc[0][j] = fmaf(a0, bv[j], acc[0][j]);
                acc[1][j] = fmaf(a1, bv[j], acc[1][j]);
                acc[2][j] = fmaf(a2, bv[j], acc[2][j]);
                acc[3][j] = fmaf(a3, bv[j], acc[3][j]);
            }
        }
        __syncthreads();
    }
    #pragma unroll
    for (int mm = 0; mm < 4; ++mm) {
        int gn = n0 + tm * 4 + mm;
        if (gn < n) {
            float vals[NN];
            #pragma unroll
            for (int j = 0; j < NN; ++j)
                vals[j] = fmaxf(acc[mm][j] + bias[tn * NN + j], 0.f);
            #pragma unroll
            for (int j4 = 0; j4 < NN; j4 += 4) {
                float4 r = {vals[j4], vals[j4 + 1], vals[j4 + 2], vals[j4 + 3]};
                *reinterpret_cast<float4*>(out + (long)gn * outs + tn * NN + j4) = r;
            }
            if constexpr (WB) {
                unsigned pk[NN / 2];
                #pragma unroll
                for (int j = 0; j < NN / 2; ++j)
                    pk[j] = (unsigned)f2bf(vals[2 * j]) | ((unsigned)f2bf(vals[2 * j + 1]) << 16);
                if constexpr (NN == 8) {
                    uint4 w = {pk[0], pk[1], pk[2], pk[3]};
                    reinterpret_cast<uint4*>(outb + (size_t)gn * DOUT)[tn] = w;
                } else {
                    uint2 w = {pk[0], pk[1]};
                    reinterpret_cast<uint2*>(outb + (size_t)gn * DOUT)[tn] = w;
                }
            }
        }
    }
}

extern "C" void kernel_launch(void* const* d_in, const int* in_sizes, int n_in,
                              void* d_out, int out_size, void* d_ws, size_t ws_size,
                              hipStream_t stream) {
    const float* x   = (const float*)d_in[0];
    const int*   ei  = (const int*)d_in[1];
    const float* W1l = (const float*)d_in[2];
    const float* b1  = (const float*)d_in[3];
    const float* W1r = (const float*)d_in[4];
    const float* W2l = (const float*)d_in[5];
    const float* b2  = (const float*)d_in[6];
    const float* W2r = (const float*)d_in[7];
    const float* W3l = (const float*)d_in[8];
    const float* b3  = (const float*)d_in[9];
    const float* W3r = (const float*)d_in[10];
    float* out = (float*)d_out;

    const int* src = ei;
    const int* dst = ei + N_EDGES;

    int* wsi = (int*)d_ws;
    int*   cnt      = wsi;                    // NP
    int*   cursor   = wsi + NP;               // NP
    int*   total    = wsi + 2 * NP;           // 64 (padded)
    int*   row_ptr  = wsi + 2 * NP + 64;      // NP
    float* inv_deg  = (float*)(wsi + 3 * NP + 64);
    int*   edge_src = wsi + 4 * NP + 64;      // E
    float* Bt1  = (float*)(edge_src + N_EDGES);
    float* Bt2  = Bt1 + 256 * 128;
    float* Bt3  = Bt2 + 256 * 64;
    float* mean = Bt3 + 128 * 128;            // N*128 f32
    unsigned short* featb = (unsigned short*)(mean + (size_t)N_NODES * 128);  // N*128 bf16 (aliased xb/h1b/h2b)

    // zero cnt+cursor+total
    hipMemsetAsync(cnt, 0, (size_t)(2 * NP + 64) * 4, stream);

    const int EB = (N_EDGES + 255) / 256;
    count_kernel<<<EB, 256, 0, stream>>>(dst, cnt, N_EDGES);
    assign_kernel<<<NP / 256, 256, 0, stream>>>(cnt, row_ptr, inv_deg, total, N_NODES);
    fill_kernel<<<EB, 256, 0, stream>>>(src, dst, row_ptr, cursor, edge_src, N_EDGES);

    build_bt_kernel<<<(2 * 128 * 128 + 255) / 256, 256, 0, stream>>>(W1l, W1r, Bt1, 128, 128);
    build_bt_kernel<<<(2 * 128 * 64 + 255) / 256, 256, 0, stream>>>(W2l, W2r, Bt2, 128, 64);
    build_bt_kernel<<<(2 * 64 * 128 + 255) / 256, 256, 0, stream>>>(W3l, W3r, Bt3, 64, 128);

    cvt_kernel<<<(N_NODES * 128 / 4 + 255) / 256, 256, 0, stream>>>(x, featb, N_NODES * 128 / 4);

    const int AGG_BLOCKS = (N_NODES + 3) / 4;
    const int GEMM_BLOCKS = (N_NODES + 63) / 64;

    // layer 1: gather bf16(x); gemm writes h1 (out cols 0..127) + bf16 copy into featb
    agg_kernel<128><<<AGG_BLOCKS, 256, 0, stream>>>(featb, row_ptr, cnt, edge_src, inv_deg, mean, N_NODES);
    gemm_kernel<256, 128, true><<<GEMM_BLOCKS, 256, 0, stream>>>(mean, 128, x, 128, Bt1, b1, out, 320, featb, N_NODES);

    // layer 2: gather bf16(h1); gemm writes h2 (cols 128..191) + bf16 copy into featb
    agg_kernel<128><<<AGG_BLOCKS, 256, 0, stream>>>(featb, row_ptr, cnt, edge_src, inv_deg, mean, N_NODES);
    gemm_kernel<256, 64, true><<<GEMM_BLOCKS, 256, 0, stream>>>(mean, 128, out, 320, Bt2, b2, out + 128, 320, featb, N_NODES);

    // layer 3: gather bf16(h2); gemm writes h3 (cols 192..319)
    agg_kernel<64><<<AGG_BLOCKS, 256, 0, stream>>>(featb, row_ptr, cnt, edge_src, inv_deg, mean, N_NODES);
    gemm_kernel<128, 128, false><<<GEMM_BLOCKS, 256, 0, stream>>>(mean, 64, out + 128, 320, Bt3, b3, out + 192, 320, nullptr, N_NODES);
}

// Round 3
// 282.446 us; speedup vs baseline: 1.6348x; 1.1685x over previous
//
#include <hip/hip_runtime.h>
#include <hip/hip_bf16.h>

#define N_NODES 50000
#define N_EDGES 800000

constexpr int NP = 50176;  // N_NODES padded to 256

typedef __attribute__((ext_vector_type(8))) short bf16x8;
typedef __attribute__((ext_vector_type(4))) float f32x4;

__device__ __forceinline__ unsigned short f2bf(float f) {
    unsigned u = __float_as_uint(f);
    u += 0x7FFFu + ((u >> 16) & 1u);   // round-nearest-even
    return (unsigned short)(u >> 16);
}

// ---------------- CSR build ----------------
__global__ void count_kernel(const int* __restrict__ dst, int* __restrict__ cnt, int E) {
    int i = blockIdx.x * blockDim.x + threadIdx.x;
    if (i < E) atomicAdd(&cnt[dst[i]], 1);
}

// wave-scan + one atomic per wave assigns row offsets
__global__ void assign_kernel(const int* __restrict__ cnt, int* __restrict__ row_ptr,
                              float* __restrict__ inv_deg, int* __restrict__ total, int n) {
    int i = blockIdx.x * blockDim.x + threadIdx.x;
    int lane = threadIdx.x & 63;
    int v = (i < n) ? cnt[i] : 0;
    int s = v;
    #pragma unroll
    for (int off = 1; off < 64; off <<= 1) {
        int t = __shfl_up(s, off);
        if (lane >= off) s += t;
    }
    int base = 0;
    if (lane == 63) base = atomicAdd(total, s);
    base = __shfl(base, 63);
    if (i < n) {
        row_ptr[i] = base + s - v;
        inv_deg[i] = 1.0f / (float)(v > 1 ? v : 1);
    }
}

__global__ void fill_kernel(const int* __restrict__ src, const int* __restrict__ dst,
                            const int* __restrict__ row_ptr, int* __restrict__ cursor,
                            int* __restrict__ edge_src, int E) {
    int i = blockIdx.x * blockDim.x + threadIdx.x;
    if (i < E) {
        int d = dst[i];
        int p = atomicAdd(&cursor[d], 1);
        edge_src[row_ptr[d] + p] = src[i];
    }
}

// Wcat[n][k] = bf16( k<din ? Wl[n][k] : Wr[n][k-din] )   -- B^T layout for MFMA
__global__ void build_wcat_kernel(const float* __restrict__ Wl, const float* __restrict__ Wr,
                                  unsigned short* __restrict__ Wc, int din, int dout) {
    int idx = blockIdx.x * blockDim.x + threadIdx.x;
    int K = 2 * din;
    if (idx >= dout * K) return;
    int nrow = idx / K;
    int k = idx - nrow * K;
    float v = (k < din) ? Wl[nrow * din + k] : Wr[nrow * din + (k - din)];
    Wc[idx] = f2bf(v);
}

// x (f32, dense 128) -> bf16 dense
__global__ void cvt_kernel(const float* __restrict__ src, unsigned short* __restrict__ dstb, int total4) {
    int i = blockIdx.x * blockDim.x + threadIdx.x;
    if (i >= total4) return;
    float4 v = reinterpret_cast<const float4*>(src)[i];
    uint2 p;
    p.x = (unsigned)f2bf(v.x) | ((unsigned)f2bf(v.y) << 16);
    p.y = (unsigned)f2bf(v.z) | ((unsigned)f2bf(v.w) << 16);
    reinterpret_cast<uint2*>(dstb)[i] = p;
}

// ---------------- mean aggregation: one wave per node, bf16 gather, bf16 mean out ----------------
template<int D>
__global__ __launch_bounds__(256) void agg_kernel(
        const unsigned short* __restrict__ hb,     // dense bf16 [n][D]
        const int* __restrict__ row_ptr, const int* __restrict__ cnt,
        const int* __restrict__ edge_src,
        const float* __restrict__ inv_deg, unsigned short* __restrict__ meanb, int n) {
    constexpr int LPR = D / 8;      // lanes per row
    constexpr int EPW = 64 / LPR;   // edges in parallel per wave
    int wid = (blockIdx.x * 256 + threadIdx.x) >> 6;
    int lane = threadIdx.x & 63;
    if (wid >= n) return;
    int beg = row_ptr[wid];
    int end = beg + cnt[wid];
    float inv = inv_deg[wid];
    int sub = lane / LPR;
    int li = lane % LPR;

    float acc[8];
    #pragma unroll
    for (int j = 0; j < 8; ++j) acc[j] = 0.f;

    for (int e0 = beg; e0 < end; e0 += 2 * EPW) {
        int e = e0 + sub;
        int e2 = e + EPW;
        uint4 v0 = {0u, 0u, 0u, 0u}, v1 = {0u, 0u, 0u, 0u};
        if (e < end) {
            int s0 = edge_src[e];
            v0 = *reinterpret_cast<const uint4*>(hb + (size_t)s0 * D + li * 8);
        }
        if (e2 < end) {
            int s1 = edge_src[e2];
            v1 = *reinterpret_cast<const uint4*>(hb + (size_t)s1 * D + li * 8);
        }
        unsigned w;
        #define ACCW(u, j0) w = (u); acc[j0] += __uint_as_float(w << 16); acc[j0+1] += __uint_as_float(w & 0xFFFF0000u)
        ACCW(v0.x, 0); ACCW(v0.y, 2); ACCW(v0.z, 4); ACCW(v0.w, 6);
        ACCW(v1.x, 0); ACCW(v1.y, 2); ACCW(v1.z, 4); ACCW(v1.w, 6);
        #undef ACCW
    }
    #pragma unroll
    for (int off = LPR; off < 64; off <<= 1) {
        #pragma unroll
        for (int j = 0; j < 8; ++j) acc[j] += __shfl_xor(acc[j], off);
    }
    if (lane < LPR) {
        uint4 w;
        w.x = (unsigned)f2bf(acc[0] * inv) | ((unsigned)f2bf(acc[1] * inv) << 16);
        w.y = (unsigned)f2bf(acc[2] * inv) | ((unsigned)f2bf(acc[3] * inv) << 16);
        w.z = (unsigned)f2bf(acc[4] * inv) | ((unsigned)f2bf(acc[5] * inv) << 16);
        w.w = (unsigned)f2bf(acc[6] * inv) | ((unsigned)f2bf(acc[7] * inv) << 16);
        *reinterpret_cast<uint4*>(meanb + (size_t)wid * D + li * 8) = w;
    }
}

// ---------------- MFMA GEMM: out = relu([meanb | featb] @ Wcat^T + bias) ----------------
// LDS-free: A-frags held in registers (one wave = 16 nodes), B-frags streamed from
// L1/L2-resident Wcat ([DOUT][K] bf16, i.e. B^T row-major -- MFMA's native layout).
// A-frag: lane holds A[m = lane&15][k = kk*32 + (lane>>4)*8 + j]
// B-frag: lane holds B[k][n = lane&15], same k-chunking
// D-frag: lane, reg r -> C[m = (lane>>4)*4 + r][n = lane&15]   [m89/m91 verified]
template<int K, int DOUT, bool WB>
__global__ __launch_bounds__(256) void mfma_gemm_kernel(
        const unsigned short* __restrict__ Ab,   // meanb [n][DIN]
        const unsigned short* __restrict__ Fb,   // self features bf16 [n][DIN]
        const unsigned short* __restrict__ Wc,   // Wcat [DOUT][K]
        const float* __restrict__ bias,
        float* __restrict__ out, int outs,
        unsigned short* __restrict__ outb, int n) {
    constexpr int DIN = K / 2;
    constexpr int NT = DOUT / 16;   // n-tiles per wave
    constexpr int KK = K / 32;      // k-frags
    int wave = threadIdx.x >> 6;
    int lane = threadIdx.x & 63;
    int m0 = blockIdx.x * 64 + wave * 16;
    int arow = lane & 15;
    int kseg = lane >> 4;
    int node = m0 + arow;
    int nc = (node < n) ? node : 0;

    bf16x8 a[KK];
    #pragma unroll
    for (int kk = 0; kk < KK; ++kk) {
        int k = kk * 32 + kseg * 8;
        const unsigned short* p = (k < DIN) ? (Ab + (size_t)nc * DIN + k)
                                            : (Fb + (size_t)nc * DIN + (k - DIN));
        a[kk] = *reinterpret_cast<const bf16x8*>(p);
    }

    f32x4 acc[NT];
    #pragma unroll
    for (int t = 0; t < NT; ++t) acc[t] = {0.f, 0.f, 0.f, 0.f};

    #pragma unroll
    for (int t = 0; t < NT; ++t) {
        const unsigned short* wp = Wc + (size_t)(t * 16 + arow) * K + kseg * 8;
        #pragma unroll
        for (int kk = 0; kk < KK; ++kk) {
            bf16x8 b = *reinterpret_cast<const bf16x8*>(wp + kk * 32);
            acc[t] = __builtin_amdgcn_mfma_f32_16x16x32_bf16(a[kk], b, acc[t], 0, 0, 0);
        }
    }

    // epilogue: bias + relu, f32 out (strided concat) + optional bf16 copy
    int crow0 = m0 + kseg * 4;
    #pragma unroll
    for (int r = 0; r < 4; ++r) {
        int gn = crow0 + r;
        if (gn < n) {
            #pragma unroll
            for (int t = 0; t < NT; ++t) {
                int col = t * 16 + arow;
                float v = fmaxf(acc[t][r] + bias[col], 0.f);
                out[(size_t)gn * outs + col] = v;
                if constexpr (WB) outb[(size_t)gn * DOUT + col] = f2bf(v);
            }
        }
    }
}

extern "C" void kernel_launch(void* const* d_in, const int* in_sizes, int n_in,
                              void* d_out, int out_size, void* d_ws, size_t ws_size,
                              hipStream_t stream) {
    const float* x   = (const float*)d_in[0];
    const int*   ei  = (const int*)d_in[1];
    const float* W1l = (const float*)d_in[2];
    const float* b1  = (const float*)d_in[3];
    const float* W1r = (const float*)d_in[4];
    const float* W2l = (const float*)d_in[5];
    const float* b2  = (const float*)d_in[6];
    const float* W2r = (const float*)d_in[7];
    const float* W3l = (const float*)d_in[8];
    const float* b3  = (const float*)d_in[9];
    const float* W3r = (const float*)d_in[10];
    float* out = (float*)d_out;

    const int* src = ei;
    const int* dst = ei + N_EDGES;

    int* wsi = (int*)d_ws;
    int*   cnt      = wsi;                    // NP
    int*   cursor   = wsi + NP;               // NP
    int*   total    = wsi + 2 * NP;           // 64 (padded)
    int*   row_ptr  = wsi + 2 * NP + 64;      // NP
    float* inv_deg  = (float*)(wsi + 3 * NP + 64);
    int*   edge_src = wsi + 4 * NP + 64;      // E
    unsigned short* Wc1 = (unsigned short*)(edge_src + N_EDGES);  // 128*256
    unsigned short* Wc2 = Wc1 + 128 * 256;                        // 64*256
    unsigned short* Wc3 = Wc2 + 64 * 256;                         // 128*128
    unsigned short* meanb = Wc3 + 128 * 128;                      // N*128 bf16
    unsigned short* featb = meanb + (size_t)N_NODES * 128;        // N*128 bf16 (x -> h1, in-place)
    unsigned short* h2b   = featb + (size_t)N_NODES * 128;        // N*64  bf16

    hipMemsetAsync(cnt, 0, (size_t)(2 * NP + 64) * 4, stream);

    const int EB = (N_EDGES + 255) / 256;
    count_kernel<<<EB, 256, 0, stream>>>(dst, cnt, N_EDGES);
    assign_kernel<<<NP / 256, 256, 0, stream>>>(cnt, row_ptr, inv_deg, total, N_NODES);
    fill_kernel<<<EB, 256, 0, stream>>>(src, dst, row_ptr, cursor, edge_src, N_EDGES);

    build_wcat_kernel<<<(128 * 256 + 255) / 256, 256, 0, stream>>>(W1l, W1r, Wc1, 128, 128);
    build_wcat_kernel<<<(64 * 256 + 255) / 256, 256, 0, stream>>>(W2l, W2r, Wc2, 128, 64);
    build_wcat_kernel<<<(128 * 128 + 255) / 256, 256, 0, stream>>>(W3l, W3r, Wc3, 64, 128);

    cvt_kernel<<<(N_NODES * 128 / 4 + 255) / 256, 256, 0, stream>>>(x, featb, N_NODES * 128 / 4);

    const int AGG_BLOCKS = (N_NODES + 3) / 4;
    const int GEMM_BLOCKS = (N_NODES + 63) / 64;

    // layer 1: gather bf16(x); gemm reads featb(x), writes out cols [0,128) + h1 bf16 in-place into featb
    agg_kernel<128><<<AGG_BLOCKS, 256, 0, stream>>>(featb, row_ptr, cnt, edge_src, inv_deg, meanb, N_NODES);
    mfma_gemm_kernel<256, 128, true><<<GEMM_BLOCKS, 256, 0, stream>>>(meanb, featb, Wc1, b1, out, 320, featb, N_NODES);

    // layer 2: gather bf16(h1); gemm writes out cols [128,192) + h2 bf16 into h2b (separate buffer!)
    agg_kernel<128><<<AGG_BLOCKS, 256, 0, stream>>>(featb, row_ptr, cnt, edge_src, inv_deg, meanb, N_NODES);
    mfma_gemm_kernel<256, 64, true><<<GEMM_BLOCKS, 256, 0, stream>>>(meanb, featb, Wc2, b2, out + 128, 320, h2b, N_NODES);

    // layer 3: gather bf16(h2); gemm writes out cols [192,320)
    agg_kernel<64><<<AGG_BLOCKS, 256, 0, stream>>>(h2b, row_ptr, cnt, edge_src, inv_deg, meanb, N_NODES);
    mfma_gemm_kernel<128, 128, false><<<GEMM_BLOCKS, 256, 0, stream>>>(meanb, h2b, Wc3, b3, out + 192, 320, nullptr, N_NODES);
}

// Round 4
// 255.089 us; speedup vs baseline: 1.8102x; 1.1072x over previous
//
#include <hip/hip_runtime.h>
#include <hip/hip_bf16.h>

#define N_NODES 50000
#define N_EDGES 800000

constexpr int NP = 50176;  // N_NODES padded to 256

typedef __attribute__((ext_vector_type(8))) short bf16x8;
typedef __attribute__((ext_vector_type(4))) float f32x4;

__device__ __forceinline__ unsigned short f2bf(float f) {
    unsigned u = __float_as_uint(f);
    u += 0x7FFFu + ((u >> 16) & 1u);   // round-nearest-even
    return (unsigned short)(u >> 16);
}

// ---------------- CSR build ----------------
// pass 1: count in-degree AND remember each edge's slot (pays atomics once)
__global__ void count_kernel(const int* __restrict__ dst, int* __restrict__ cnt,
                             int* __restrict__ pos, int E) {
    int i = blockIdx.x * blockDim.x + threadIdx.x;
    if (i < E) pos[i] = atomicAdd(&cnt[dst[i]], 1);
}

// wave-scan + one atomic per wave assigns row offsets
__global__ void assign_kernel(const int* __restrict__ cnt, int* __restrict__ row_ptr,
                              float* __restrict__ inv_deg, int* __restrict__ total, int n) {
    int i = blockIdx.x * blockDim.x + threadIdx.x;
    int lane = threadIdx.x & 63;
    int v = (i < n) ? cnt[i] : 0;
    int s = v;
    #pragma unroll
    for (int off = 1; off < 64; off <<= 1) {
        int t = __shfl_up(s, off);
        if (lane >= off) s += t;
    }
    int base = 0;
    if (lane == 63) base = atomicAdd(total, s);
    base = __shfl(base, 63);
    if (i < n) {
        row_ptr[i] = base + s - v;
        inv_deg[i] = 1.0f / (float)(v > 1 ? v : 1);
    }
}

// pass 2: atomic-free scatter
__global__ void fill_kernel(const int* __restrict__ src, const int* __restrict__ dst,
                            const int* __restrict__ row_ptr, const int* __restrict__ pos,
                            int* __restrict__ edge_src, int E) {
    int i = blockIdx.x * blockDim.x + threadIdx.x;
    if (i < E) edge_src[row_ptr[dst[i]] + pos[i]] = src[i];
}

// Wcat[n][k] = bf16( k<din ? Wl[n][k] : Wr[n][k-din] )   -- B^T layout for MFMA
__global__ void build_wcat_kernel(const float* __restrict__ Wl, const float* __restrict__ Wr,
                                  unsigned short* __restrict__ Wc, int din, int dout) {
    int idx = blockIdx.x * blockDim.x + threadIdx.x;
    int K = 2 * din;
    if (idx >= dout * K) return;
    int nrow = idx / K;
    int k = idx - nrow * K;
    float v = (k < din) ? Wl[nrow * din + k] : Wr[nrow * din + (k - din)];
    Wc[idx] = f2bf(v);
}

// x (f32, dense 128) -> bf16 dense
__global__ void cvt_kernel(const float* __restrict__ src, unsigned short* __restrict__ dstb, int total4) {
    int i = blockIdx.x * blockDim.x + threadIdx.x;
    if (i >= total4) return;
    float4 v = reinterpret_cast<const float4*>(src)[i];
    uint2 p;
    p.x = (unsigned)f2bf(v.x) | ((unsigned)f2bf(v.y) << 16);
    p.y = (unsigned)f2bf(v.z) | ((unsigned)f2bf(v.w) << 16);
    reinterpret_cast<uint2*>(dstb)[i] = p;
}

// ---------------- mean aggregation: one wave per node, bf16 gather, bf16 mean out ----------------
template<int D>
__global__ __launch_bounds__(256) void agg_kernel(
        const unsigned short* __restrict__ hb,     // dense bf16 [n][D]
        const int* __restrict__ row_ptr, const int* __restrict__ cnt,
        const int* __restrict__ edge_src,
        const float* __restrict__ inv_deg, unsigned short* __restrict__ meanb, int n) {
    constexpr int LPR = D / 8;      // lanes per row
    constexpr int EPW = 64 / LPR;   // edges in parallel per wave
    int wid = (blockIdx.x * 256 + threadIdx.x) >> 6;
    int lane = threadIdx.x & 63;
    if (wid >= n) return;
    int beg = row_ptr[wid];
    int end = beg + cnt[wid];
    float inv = inv_deg[wid];
    int sub = lane / LPR;
    int li = lane % LPR;

    float acc[8];
    #pragma unroll
    for (int j = 0; j < 8; ++j) acc[j] = 0.f;

    for (int e0 = beg; e0 < end; e0 += 2 * EPW) {
        int e = e0 + sub;
        int e2 = e + EPW;
        uint4 v0 = {0u, 0u, 0u, 0u}, v1 = {0u, 0u, 0u, 0u};
        if (e < end) {
            int s0 = edge_src[e];
            v0 = *reinterpret_cast<const uint4*>(hb + (size_t)s0 * D + li * 8);
        }
        if (e2 < end) {
            int s1 = edge_src[e2];
            v1 = *reinterpret_cast<const uint4*>(hb + (size_t)s1 * D + li * 8);
        }
        unsigned w;
        #define ACCW(u, j0) w = (u); acc[j0] += __uint_as_float(w << 16); acc[j0+1] += __uint_as_float(w & 0xFFFF0000u)
        ACCW(v0.x, 0); ACCW(v0.y, 2); ACCW(v0.z, 4); ACCW(v0.w, 6);
        ACCW(v1.x, 0); ACCW(v1.y, 2); ACCW(v1.z, 4); ACCW(v1.w, 6);
        #undef ACCW
    }
    #pragma unroll
    for (int off = LPR; off < 64; off <<= 1) {
        #pragma unroll
        for (int j = 0; j < 8; ++j) acc[j] += __shfl_xor(acc[j], off);
    }
    if (lane < LPR) {
        uint4 w;
        w.x = (unsigned)f2bf(acc[0] * inv) | ((unsigned)f2bf(acc[1] * inv) << 16);
        w.y = (unsigned)f2bf(acc[2] * inv) | ((unsigned)f2bf(acc[3] * inv) << 16);
        w.z = (unsigned)f2bf(acc[4] * inv) | ((unsigned)f2bf(acc[5] * inv) << 16);
        w.w = (unsigned)f2bf(acc[6] * inv) | ((unsigned)f2bf(acc[7] * inv) << 16);
        *reinterpret_cast<uint4*>(meanb + (size_t)wid * D + li * 8) = w;
    }
}

// ---------------- MFMA GEMM: out = relu([meanb | featb] @ Wcat^T + bias) ----------------
// LDS-free. One wave = 16 nodes x DOUT. Loop order: kk OUTER / tile INNER so each
// stage has NT independent B-loads feeding NT independent MFMAs (different acc) --
// compiler software-pipelines next stage's loads under current MFMAs.
template<int K, int DOUT, bool WB>
__global__ __launch_bounds__(256, 3) void mfma_gemm_kernel(
        const unsigned short* __restrict__ Ab,   // meanb [n][DIN]
        const unsigned short* __restrict__ Fb,   // self features bf16 [n][DIN]
        const unsigned short* __restrict__ Wc,   // Wcat [DOUT][K]
        const float* __restrict__ bias,
        float* __restrict__ out, int outs,
        unsigned short* __restrict__ outb, int n) {
    constexpr int DIN = K / 2;
    constexpr int NT = DOUT / 16;   // n-tiles per wave
    constexpr int KK = K / 32;      // k-frags
    int wave = threadIdx.x >> 6;
    int lane = threadIdx.x & 63;
    int m0 = blockIdx.x * 64 + wave * 16;
    int arow = lane & 15;
    int kseg = lane >> 4;
    int node = m0 + arow;
    int nc = (node < n) ? node : 0;

    // preload all A-frags (KK x 4 VGPR)
    bf16x8 a[KK];
    #pragma unroll
    for (int kk = 0; kk < KK; ++kk) {
        int k = kk * 32 + kseg * 8;
        const unsigned short* p = (k < DIN) ? (Ab + (size_t)nc * DIN + k)
                                            : (Fb + (size_t)nc * DIN + (k - DIN));
        a[kk] = *reinterpret_cast<const bf16x8*>(p);
    }

    f32x4 acc[NT];
    #pragma unroll
    for (int t = 0; t < NT; ++t) acc[t] = {0.f, 0.f, 0.f, 0.f};

    const unsigned short* wbase = Wc + (size_t)arow * K + kseg * 8;
    #pragma unroll
    for (int kk = 0; kk < KK; ++kk) {
        bf16x8 b[NT];
        #pragma unroll
        for (int t = 0; t < NT; ++t)
            b[t] = *reinterpret_cast<const bf16x8*>(wbase + (size_t)t * 16 * K + kk * 32);
        #pragma unroll
        for (int t = 0; t < NT; ++t)
            acc[t] = __builtin_amdgcn_mfma_f32_16x16x32_bf16(a[kk], b[t], acc[t], 0, 0, 0);
    }

    // epilogue: bias + relu, f32 out (strided concat) + optional bf16 copy
    int crow0 = m0 + kseg * 4;
    #pragma unroll
    for (int r = 0; r < 4; ++r) {
        int gn = crow0 + r;
        if (gn < n) {
            #pragma unroll
            for (int t = 0; t < NT; ++t) {
                int col = t * 16 + arow;
                float v = fmaxf(acc[t][r] + bias[col], 0.f);
                out[(size_t)gn * outs + col] = v;
                if constexpr (WB) outb[(size_t)gn * DOUT + col] = f2bf(v);
            }
        }
    }
}

extern "C" void kernel_launch(void* const* d_in, const int* in_sizes, int n_in,
                              void* d_out, int out_size, void* d_ws, size_t ws_size,
                              hipStream_t stream) {
    const float* x   = (const float*)d_in[0];
    const int*   ei  = (const int*)d_in[1];
    const float* W1l = (const float*)d_in[2];
    const float* b1  = (const float*)d_in[3];
    const float* W1r = (const float*)d_in[4];
    const float* W2l = (const float*)d_in[5];
    const float* b2  = (const float*)d_in[6];
    const float* W2r = (const float*)d_in[7];
    const float* W3l = (const float*)d_in[8];
    const float* b3  = (const float*)d_in[9];
    const float* W3r = (const float*)d_in[10];
    float* out = (float*)d_out;

    const int* src = ei;
    const int* dst = ei + N_EDGES;

    int* wsi = (int*)d_ws;
    int*   cnt      = wsi;                    // NP
    int*   total    = wsi + NP;               // 64 (padded)
    int*   row_ptr  = wsi + NP + 64;          // NP
    float* inv_deg  = (float*)(wsi + 2 * NP + 64);
    int*   edge_src = wsi + 3 * NP + 64;      // E
    int*   pos      = edge_src + N_EDGES;     // E
    unsigned short* Wc1 = (unsigned short*)(pos + N_EDGES);       // 128*256
    unsigned short* Wc2 = Wc1 + 128 * 256;                        // 64*256
    unsigned short* Wc3 = Wc2 + 64 * 256;                         // 128*128
    unsigned short* meanb = Wc3 + 128 * 128;                      // N*128 bf16
    unsigned short* featb = meanb + (size_t)N_NODES * 128;        // N*128 bf16 (x -> h1, in-place)
    unsigned short* h2b   = featb + (size_t)N_NODES * 128;        // N*64  bf16

    hipMemsetAsync(cnt, 0, (size_t)(NP + 64) * 4, stream);

    const int EB = (N_EDGES + 255) / 256;
    count_kernel<<<EB, 256, 0, stream>>>(dst, cnt, pos, N_EDGES);
    assign_kernel<<<NP / 256, 256, 0, stream>>>(cnt, row_ptr, inv_deg, total, N_NODES);
    fill_kernel<<<EB, 256, 0, stream>>>(src, dst, row_ptr, pos, edge_src, N_EDGES);

    build_wcat_kernel<<<(128 * 256 + 255) / 256, 256, 0, stream>>>(W1l, W1r, Wc1, 128, 128);
    build_wcat_kernel<<<(64 * 256 + 255) / 256, 256, 0, stream>>>(W2l, W2r, Wc2, 128, 64);
    build_wcat_kernel<<<(128 * 128 + 255) / 256, 256, 0, stream>>>(W3l, W3r, Wc3, 64, 128);

    cvt_kernel<<<(N_NODES * 128 / 4 + 255) / 256, 256, 0, stream>>>(x, featb, N_NODES * 128 / 4);

    const int AGG_BLOCKS = (N_NODES + 3) / 4;
    const int GEMM_BLOCKS = (N_NODES + 63) / 64;

    // layer 1: gather bf16(x); gemm reads featb(x), writes out cols [0,128) + h1 bf16 in-place into featb
    agg_kernel<128><<<AGG_BLOCKS, 256, 0, stream>>>(featb, row_ptr, cnt, edge_src, inv_deg, meanb, N_NODES);
    mfma_gemm_kernel<256, 128, true><<<GEMM_BLOCKS, 256, 0, stream>>>(meanb, featb, Wc1, b1, out, 320, featb, N_NODES);

    // layer 2: gather bf16(h1); gemm writes out cols [128,192) + h2 bf16 into h2b (separate buffer!)
    agg_kernel<128><<<AGG_BLOCKS, 256, 0, stream>>>(featb, row_ptr, cnt, edge_src, inv_deg, meanb, N_NODES);
    mfma_gemm_kernel<256, 64, true><<<GEMM_BLOCKS, 256, 0, stream>>>(meanb, featb, Wc2, b2, out + 128, 320, h2b, N_NODES);

    // layer 3: gather bf16(h2); gemm writes out cols [192,320)
    agg_kernel<64><<<AGG_BLOCKS, 256, 0, stream>>>(h2b, row_ptr, cnt, edge_src, inv_deg, meanb, N_NODES);
    mfma_gemm_kernel<128, 128, false><<<GEMM_BLOCKS, 256, 0, stream>>>(meanb, h2b, Wc3, b3, out + 192, 320, nullptr, N_NODES);
}

// Round 5
// 229.907 us; speedup vs baseline: 2.0084x; 1.1095x over previous
//
#include <hip/hip_runtime.h>
#include <hip/hip_bf16.h>

#define N_NODES 50000
#define N_EDGES 800000

constexpr int NP = 50176;  // N_NODES padded to 256

typedef __attribute__((ext_vector_type(8))) short bf16x8;
typedef __attribute__((ext_vector_type(4))) float f32x4;

__device__ __forceinline__ unsigned short f2bf(float f) {
    unsigned u = __float_as_uint(f);
    u += 0x7FFFu + ((u >> 16) & 1u);   // round-nearest-even
    return (unsigned short)(u >> 16);
}

// ---------------- CSR build ----------------
__global__ void count_kernel(const int* __restrict__ dst, int* __restrict__ cnt,
                             int* __restrict__ pos, int E) {
    int i = blockIdx.x * blockDim.x + threadIdx.x;
    if (i < E) pos[i] = atomicAdd(&cnt[dst[i]], 1);
}

__global__ void assign_kernel(const int* __restrict__ cnt, int* __restrict__ row_ptr,
                              float* __restrict__ inv_deg, int* __restrict__ total, int n) {
    int i = blockIdx.x * blockDim.x + threadIdx.x;
    int lane = threadIdx.x & 63;
    int v = (i < n) ? cnt[i] : 0;
    int s = v;
    #pragma unroll
    for (int off = 1; off < 64; off <<= 1) {
        int t = __shfl_up(s, off);
        if (lane >= off) s += t;
    }
    int base = 0;
    if (lane == 63) base = atomicAdd(total, s);
    base = __shfl(base, 63);
    if (i < n) {
        row_ptr[i] = base + s - v;
        inv_deg[i] = 1.0f / (float)(v > 1 ? v : 1);
    }
}

__global__ void fill_kernel(const int* __restrict__ src, const int* __restrict__ dst,
                            const int* __restrict__ row_ptr, const int* __restrict__ pos,
                            int* __restrict__ edge_src, int E) {
    int i = blockIdx.x * blockDim.x + threadIdx.x;
    if (i < E) edge_src[row_ptr[dst[i]] + pos[i]] = src[i];
}

// Wcat[n][k] = bf16( k<din ? Wl[n][k] : Wr[n][k-din] )   -- B^T layout for MFMA
__global__ void build_wcat_kernel(const float* __restrict__ Wl, const float* __restrict__ Wr,
                                  unsigned short* __restrict__ Wc, int din, int dout) {
    int idx = blockIdx.x * blockDim.x + threadIdx.x;
    int K = 2 * din;
    if (idx >= dout * K) return;
    int nrow = idx / K;
    int k = idx - nrow * K;
    float v = (k < din) ? Wl[nrow * din + k] : Wr[nrow * din + (k - din)];
    Wc[idx] = f2bf(v);
}

__global__ void cvt_kernel(const float* __restrict__ src, unsigned short* __restrict__ dstb, int total4) {
    int i = blockIdx.x * blockDim.x + threadIdx.x;
    if (i >= total4) return;
    float4 v = reinterpret_cast<const float4*>(src)[i];
    uint2 p;
    p.x = (unsigned)f2bf(v.x) | ((unsigned)f2bf(v.y) << 16);
    p.y = (unsigned)f2bf(v.z) | ((unsigned)f2bf(v.w) << 16);
    reinterpret_cast<uint2*>(dstb)[i] = p;
}

// ---------------- mean aggregation: one wave per node, bf16 gather, bf16 mean out ----------------
template<int D>
__global__ __launch_bounds__(256) void agg_kernel(
        const unsigned short* __restrict__ hb,
        const int* __restrict__ row_ptr, const int* __restrict__ cnt,
        const int* __restrict__ edge_src,
        const float* __restrict__ inv_deg, unsigned short* __restrict__ meanb, int n) {
    constexpr int LPR = D / 8;
    constexpr int EPW = 64 / LPR;
    int wid = (blockIdx.x * 256 + threadIdx.x) >> 6;
    int lane = threadIdx.x & 63;
    if (wid >= n) return;
    int beg = row_ptr[wid];
    int end = beg + cnt[wid];
    float inv = inv_deg[wid];
    int sub = lane / LPR;
    int li = lane % LPR;

    float acc[8];
    #pragma unroll
    for (int j = 0; j < 8; ++j) acc[j] = 0.f;

    for (int e0 = beg; e0 < end; e0 += 2 * EPW) {
        int e = e0 + sub;
        int e2 = e + EPW;
        uint4 v0 = {0u, 0u, 0u, 0u}, v1 = {0u, 0u, 0u, 0u};
        if (e < end) {
            int s0 = edge_src[e];
            v0 = *reinterpret_cast<const uint4*>(hb + (size_t)s0 * D + li * 8);
        }
        if (e2 < end) {
            int s1 = edge_src[e2];
            v1 = *reinterpret_cast<const uint4*>(hb + (size_t)s1 * D + li * 8);
        }
        unsigned w;
        #define ACCW(u, j0) w = (u); acc[j0] += __uint_as_float(w << 16); acc[j0+1] += __uint_as_float(w & 0xFFFF0000u)
        ACCW(v0.x, 0); ACCW(v0.y, 2); ACCW(v0.z, 4); ACCW(v0.w, 6);
        ACCW(v1.x, 0); ACCW(v1.y, 2); ACCW(v1.z, 4); ACCW(v1.w, 6);
        #undef ACCW
    }
    #pragma unroll
    for (int off = LPR; off < 64; off <<= 1) {
        #pragma unroll
        for (int j = 0; j < 8; ++j) acc[j] += __shfl_xor(acc[j], off);
    }
    if (lane < LPR) {
        uint4 w;
        w.x = (unsigned)f2bf(acc[0] * inv) | ((unsigned)f2bf(acc[1] * inv) << 16);
        w.y = (unsigned)f2bf(acc[2] * inv) | ((unsigned)f2bf(acc[3] * inv) << 16);
        w.z = (unsigned)f2bf(acc[4] * inv) | ((unsigned)f2bf(acc[5] * inv) << 16);
        w.w = (unsigned)f2bf(acc[6] * inv) | ((unsigned)f2bf(acc[7] * inv) << 16);
        *reinterpret_cast<uint4*>(meanb + (size_t)wid * D + li * 8) = w;
    }
}

// ---------------- MFMA GEMM v3: B-in-registers, M-loop per wave ----------------
// Each wave owns 32 output cols (2 x 16-col tiles); B-frags (2*KK bf16x8) loaded ONCE.
// Wave loops over 4 groups of 16 nodes with ping-pong A buffers (static indexing).
// NWC = DOUT/32 col-waves; NWM = 4/NWC m-splits; block covers 16*4*NWM nodes.
template<int K, int DOUT, bool WB>
__global__ __launch_bounds__(256, 3) void mfma_gemm_kernel(
        const unsigned short* __restrict__ Ab,   // meanb [n][DIN]
        const unsigned short* __restrict__ Fb,   // self bf16 [n][DIN]
        const unsigned short* __restrict__ Wc,   // [DOUT][K]
        const float* __restrict__ bias,
        float* __restrict__ out, int outs,
        unsigned short* __restrict__ outb, int n) {
    constexpr int DIN = K / 2;
    constexpr int KK = K / 32;
    constexpr int NWC = DOUT / 32;     // 4 (DOUT=128) or 2 (DOUT=64)
    constexpr int NWM = 4 / NWC;
    constexpr int GW = 4;              // 16-node groups per wave
    constexpr int BM = 16 * GW * NWM;  // nodes per block
    int wave = threadIdx.x >> 6;
    int lane = threadIdx.x & 63;
    int wc = wave % NWC;
    int wm = wave / NWC;
    int arow = lane & 15;
    int kseg = lane >> 4;

    // B preload: 2 col-tiles x KK frags (stays in registers for the whole kernel)
    bf16x8 b0[KK], b1[KK];
    {
        const unsigned short* wp0 = Wc + (size_t)(wc * 32 + arow) * K + kseg * 8;
        const unsigned short* wp1 = wp0 + (size_t)16 * K;
        #pragma unroll
        for (int kk = 0; kk < KK; ++kk) {
            b0[kk] = *reinterpret_cast<const bf16x8*>(wp0 + kk * 32);
            b1[kk] = *reinterpret_cast<const bf16x8*>(wp1 + kk * 32);
        }
    }
    float bv0 = bias[wc * 32 + arow];
    float bv1 = bias[wc * 32 + 16 + arow];

    int g0 = blockIdx.x * (BM / 16) + wm * GW;   // first group index for this wave

    bf16x8 a0[KK], a1[KK];

    #define LOADA(g, dst)                                                          \
    {                                                                              \
        int node = (g0 + (g)) * 16 + arow;                                         \
        int ncl = node < n ? node : 0;                                             \
        _Pragma("unroll")                                                          \
        for (int kk = 0; kk < KK; ++kk) {                                          \
            int k = kk * 32 + kseg * 8;                                            \
            const unsigned short* p = (k < DIN) ? (Ab + (size_t)ncl * DIN + k)     \
                                                : (Fb + (size_t)ncl * DIN + (k - DIN)); \
            dst[kk] = *reinterpret_cast<const bf16x8*>(p);                         \
        }                                                                          \
    }

    #define COMPUTE(g, ab)                                                         \
    {                                                                              \
        f32x4 acc0 = {0.f, 0.f, 0.f, 0.f}, acc1 = {0.f, 0.f, 0.f, 0.f};           \
        _Pragma("unroll")                                                          \
        for (int kk = 0; kk < KK; ++kk) {                                          \
            acc0 = __builtin_amdgcn_mfma_f32_16x16x32_bf16(ab[kk], b0[kk], acc0, 0, 0, 0); \
            acc1 = __builtin_amdgcn_mfma_f32_16x16x32_bf16(ab[kk], b1[kk], acc1, 0, 0, 0); \
        }                                                                          \
        int gbase = (g0 + (g)) * 16 + kseg * 4;                                    \
        _Pragma("unroll")                                                          \
        for (int r = 0; r < 4; ++r) {                                              \
            int gn = gbase + r;                                                    \
            if (gn < n) {                                                          \
                int col0 = wc * 32 + arow;                                         \
                float v0 = fmaxf(acc0[r] + bv0, 0.f);                              \
                float v1 = fmaxf(acc1[r] + bv1, 0.f);                              \
                out[(size_t)gn * outs + col0] = v0;                                \
                out[(size_t)gn * outs + col0 + 16] = v1;                           \
                if constexpr (WB) {                                                \
                    outb[(size_t)gn * DOUT + col0] = f2bf(v0);                     \
                    outb[(size_t)gn * DOUT + col0 + 16] = f2bf(v1);                \
                }                                                                  \
            }                                                                      \
        }                                                                          \
    }

    LOADA(0, a0);
    #pragma unroll
    for (int gp = 0; gp < GW; gp += 2) {
        LOADA(gp + 1, a1);
        COMPUTE(gp, a0);
        if (gp + 2 < GW) LOADA(gp + 2, a0);
        COMPUTE(gp + 1, a1);
    }
    #undef LOADA
    #undef COMPUTE
}

extern "C" void kernel_launch(void* const* d_in, const int* in_sizes, int n_in,
                              void* d_out, int out_size, void* d_ws, size_t ws_size,
                              hipStream_t stream) {
    const float* x   = (const float*)d_in[0];
    const int*   ei  = (const int*)d_in[1];
    const float* W1l = (const float*)d_in[2];
    const float* b1  = (const float*)d_in[3];
    const float* W1r = (const float*)d_in[4];
    const float* W2l = (const float*)d_in[5];
    const float* b2  = (const float*)d_in[6];
    const float* W2r = (const float*)d_in[7];
    const float* W3l = (const float*)d_in[8];
    const float* b3  = (const float*)d_in[9];
    const float* W3r = (const float*)d_in[10];
    float* out = (float*)d_out;

    const int* src = ei;
    const int* dst = ei + N_EDGES;

    int* wsi = (int*)d_ws;
    int*   cnt      = wsi;                    // NP
    int*   total    = wsi + NP;               // 64
    int*   row_ptr  = wsi + NP + 64;          // NP
    float* inv_deg  = (float*)(wsi + 2 * NP + 64);
    int*   edge_src = wsi + 3 * NP + 64;      // E
    int*   pos      = edge_src + N_EDGES;     // E
    unsigned short* Wc1 = (unsigned short*)(pos + N_EDGES);       // 128*256
    unsigned short* Wc2 = Wc1 + 128 * 256;                        // 64*256
    unsigned short* Wc3 = Wc2 + 64 * 256;                         // 128*128
    unsigned short* meanb = Wc3 + 128 * 128;                      // N*128 bf16
    unsigned short* xb  = meanb + (size_t)N_NODES * 128;          // N*128 bf16
    unsigned short* h1b = xb + (size_t)N_NODES * 128;             // N*128 bf16
    unsigned short* h2b = h1b + (size_t)N_NODES * 128;            // N*64  bf16

    hipMemsetAsync(cnt, 0, (size_t)(NP + 64) * 4, stream);

    const int EB = (N_EDGES + 255) / 256;
    count_kernel<<<EB, 256, 0, stream>>>(dst, cnt, pos, N_EDGES);
    assign_kernel<<<NP / 256, 256, 0, stream>>>(cnt, row_ptr, inv_deg, total, N_NODES);
    fill_kernel<<<EB, 256, 0, stream>>>(src, dst, row_ptr, pos, edge_src, N_EDGES);

    build_wcat_kernel<<<(128 * 256 + 255) / 256, 256, 0, stream>>>(W1l, W1r, Wc1, 128, 128);
    build_wcat_kernel<<<(64 * 256 + 255) / 256, 256, 0, stream>>>(W2l, W2r, Wc2, 128, 64);
    build_wcat_kernel<<<(128 * 128 + 255) / 256, 256, 0, stream>>>(W3l, W3r, Wc3, 64, 128);

    cvt_kernel<<<(N_NODES * 128 / 4 + 255) / 256, 256, 0, stream>>>(x, xb, N_NODES * 128 / 4);

    const int AGG_BLOCKS = (N_NODES + 3) / 4;
    // blocks: DOUT=128 -> 64 nodes/block; DOUT=64 -> 128 nodes/block
    const int GB64  = (N_NODES + 63) / 64;     // 782
    const int GB128 = (N_NODES + 127) / 128;   // 391

    // layer 1
    agg_kernel<128><<<AGG_BLOCKS, 256, 0, stream>>>(xb, row_ptr, cnt, edge_src, inv_deg, meanb, N_NODES);
    mfma_gemm_kernel<256, 128, true><<<GB64, 256, 0, stream>>>(meanb, xb, Wc1, b1, out, 320, h1b, N_NODES);

    // layer 2
    agg_kernel<128><<<AGG_BLOCKS, 256, 0, stream>>>(h1b, row_ptr, cnt, edge_src, inv_deg, meanb, N_NODES);
    mfma_gemm_kernel<256, 64, true><<<GB128, 256, 0, stream>>>(meanb, h1b, Wc2, b2, out + 128, 320, h2b, N_NODES);

    // layer 3
    agg_kernel<64><<<AGG_BLOCKS, 256, 0, stream>>>(h2b, row_ptr, cnt, edge_src, inv_deg, meanb, N_NODES);
    mfma_gemm_kernel<128, 128, false><<<GB64, 256, 0, stream>>>(meanb, h2b, Wc3, b3, out + 192, 320, nullptr, N_NODES);
}

// Round 6
// 222.476 us; speedup vs baseline: 2.0755x; 1.0334x over previous
//
#include <hip/hip_runtime.h>
#include <hip/hip_bf16.h>

#define N_NODES 50000
#define N_EDGES 800000

constexpr int NP = 50176;       // N_NODES padded to 256
constexpr int EB = (N_EDGES + 255) / 256;        // 3125 blocks for edge-parallel work
constexpr int WCB = 256;                          // 65536 wcat elements / 256
constexpr int CVB = (N_NODES * 128 / 4 + 255) / 256;  // 6250 cvt blocks

typedef __attribute__((ext_vector_type(8))) short bf16x8;
typedef __attribute__((ext_vector_type(4))) float f32x4;

__device__ __forceinline__ unsigned short f2bf(float f) {
    unsigned u = __float_as_uint(f);
    u += 0x7FFFu + ((u >> 16) & 1u);   // round-nearest-even
    return (unsigned short)(u >> 16);
}

// ---------------- zero counters (hipMemsetAsync/fillBuffer has ~40us fixed cost) ----------------
__global__ void zero_kernel(int* __restrict__ p, int n) {
    int i = blockIdx.x * 256 + threadIdx.x;
    if (i < n) p[i] = 0;
}

// ---------------- fused prep: edge count (atomics) + Wcat builds + x->bf16 cvt ----------------
__global__ __launch_bounds__(256) void prep_kernel(
        const int* __restrict__ dst, int* __restrict__ cnt, int* __restrict__ pos,
        const float* __restrict__ W1l, const float* __restrict__ W1r,
        const float* __restrict__ W2l, const float* __restrict__ W2r,
        const float* __restrict__ W3l, const float* __restrict__ W3r,
        unsigned short* __restrict__ Wc1, unsigned short* __restrict__ Wc2,
        unsigned short* __restrict__ Wc3,
        const float* __restrict__ x, unsigned short* __restrict__ xb) {
    int b = blockIdx.x;
    int tid = threadIdx.x;
    if (b < EB) {
        // in-degree count + slot assignment (the only atomic pass)
        int i = b * 256 + tid;
        if (i < N_EDGES) pos[i] = atomicAdd(&cnt[dst[i]], 1);
    } else if (b < EB + WCB) {
        // Wcat[n][k] = bf16( k<din ? Wl[n][k] : Wr[n][k-din] )  -- B^T layout for MFMA
        int idx = (b - EB) * 256 + tid;   // [0, 65536)
        if (idx < 32768) {
            int nr = idx >> 8, k = idx & 255;
            float v = (k < 128) ? W1l[nr * 128 + k] : W1r[nr * 128 + (k - 128)];
            Wc1[idx] = f2bf(v);
        } else if (idx < 49152) {
            int j = idx - 32768;
            int nr = j >> 8, k = j & 255;
            float v = (k < 128) ? W2l[nr * 128 + k] : W2r[nr * 128 + (k - 128)];
            Wc2[j] = f2bf(v);
        } else {
            int j = idx - 49152;
            int nr = j >> 7, k = j & 127;
            float v = (k < 64) ? W3l[nr * 64 + k] : W3r[nr * 64 + (k - 64)];
            Wc3[j] = f2bf(v);
        }
    } else {
        // x (f32) -> bf16 dense, 4 elems/thread
        int i = (b - EB - WCB) * 256 + tid;
        if (i < N_NODES * 128 / 4) {
            float4 v = reinterpret_cast<const float4*>(x)[i];
            uint2 p;
            p.x = (unsigned)f2bf(v.x) | ((unsigned)f2bf(v.y) << 16);
            p.y = (unsigned)f2bf(v.z) | ((unsigned)f2bf(v.w) << 16);
            reinterpret_cast<uint2*>(xb)[i] = p;
        }
    }
}

__global__ void assign_kernel(const int* __restrict__ cnt, int* __restrict__ row_ptr,
                              float* __restrict__ inv_deg, int* __restrict__ total, int n) {
    int i = blockIdx.x * blockDim.x + threadIdx.x;
    int lane = threadIdx.x & 63;
    int v = (i < n) ? cnt[i] : 0;
    int s = v;
    #pragma unroll
    for (int off = 1; off < 64; off <<= 1) {
        int t = __shfl_up(s, off);
        if (lane >= off) s += t;
    }
    int base = 0;
    if (lane == 63) base = atomicAdd(total, s);
    base = __shfl(base, 63);
    if (i < n) {
        row_ptr[i] = base + s - v;
        inv_deg[i] = 1.0f / (float)(v > 1 ? v : 1);
    }
}

// atomic-free scatter
__global__ void fill_kernel(const int* __restrict__ src, const int* __restrict__ dst,
                            const int* __restrict__ row_ptr, const int* __restrict__ pos,
                            int* __restrict__ edge_src, int E) {
    int i = blockIdx.x * blockDim.x + threadIdx.x;
    if (i < E) edge_src[row_ptr[dst[i]] + pos[i]] = src[i];
}

// ---------------- mean aggregation: one wave per node, bf16 gather, bf16 mean out ----------------
template<int D>
__global__ __launch_bounds__(256) void agg_kernel(
        const unsigned short* __restrict__ hb,
        const int* __restrict__ row_ptr, const int* __restrict__ cnt,
        const int* __restrict__ edge_src,
        const float* __restrict__ inv_deg, unsigned short* __restrict__ meanb, int n) {
    constexpr int LPR = D / 8;
    constexpr int EPW = 64 / LPR;
    int wid = (blockIdx.x * 256 + threadIdx.x) >> 6;
    int lane = threadIdx.x & 63;
    if (wid >= n) return;
    int beg = row_ptr[wid];
    int end = beg + cnt[wid];
    float inv = inv_deg[wid];
    int sub = lane / LPR;
    int li = lane % LPR;

    float acc[8];
    #pragma unroll
    for (int j = 0; j < 8; ++j) acc[j] = 0.f;

    for (int e0 = beg; e0 < end; e0 += 2 * EPW) {
        int e = e0 + sub;
        int e2 = e + EPW;
        uint4 v0 = {0u, 0u, 0u, 0u}, v1 = {0u, 0u, 0u, 0u};
        if (e < end) {
            int s0 = edge_src[e];
            v0 = *reinterpret_cast<const uint4*>(hb + (size_t)s0 * D + li * 8);
        }
        if (e2 < end) {
            int s1 = edge_src[e2];
            v1 = *reinterpret_cast<const uint4*>(hb + (size_t)s1 * D + li * 8);
        }
        unsigned w;
        #define ACCW(u, j0) w = (u); acc[j0] += __uint_as_float(w << 16); acc[j0+1] += __uint_as_float(w & 0xFFFF0000u)
        ACCW(v0.x, 0); ACCW(v0.y, 2); ACCW(v0.z, 4); ACCW(v0.w, 6);
        ACCW(v1.x, 0); ACCW(v1.y, 2); ACCW(v1.z, 4); ACCW(v1.w, 6);
        #undef ACCW
    }
    #pragma unroll
    for (int off = LPR; off < 64; off <<= 1) {
        #pragma unroll
        for (int j = 0; j < 8; ++j) acc[j] += __shfl_xor(acc[j], off);
    }
    if (lane < LPR) {
        uint4 w;
        w.x = (unsigned)f2bf(acc[0] * inv) | ((unsigned)f2bf(acc[1] * inv) << 16);
        w.y = (unsigned)f2bf(acc[2] * inv) | ((unsigned)f2bf(acc[3] * inv) << 16);
        w.z = (unsigned)f2bf(acc[4] * inv) | ((unsigned)f2bf(acc[5] * inv) << 16);
        w.w = (unsigned)f2bf(acc[6] * inv) | ((unsigned)f2bf(acc[7] * inv) << 16);
        *reinterpret_cast<uint4*>(meanb + (size_t)wid * D + li * 8) = w;
    }
}

// ---------------- MFMA GEMM v3: B-in-registers, M-loop per wave ----------------
template<int K, int DOUT, bool WB>
__global__ __launch_bounds__(256, 3) void mfma_gemm_kernel(
        const unsigned short* __restrict__ Ab,
        const unsigned short* __restrict__ Fb,
        const unsigned short* __restrict__ Wc,
        const float* __restrict__ bias,
        float* __restrict__ out, int outs,
        unsigned short* __restrict__ outb, int n) {
    constexpr int DIN = K / 2;
    constexpr int KK = K / 32;
    constexpr int NWC = DOUT / 32;
    constexpr int NWM = 4 / NWC;
    constexpr int GW = 4;
    constexpr int BM = 16 * GW * NWM;
    int wave = threadIdx.x >> 6;
    int lane = threadIdx.x & 63;
    int wc = wave % NWC;
    int wm = wave / NWC;
    int arow = lane & 15;
    int kseg = lane >> 4;

    bf16x8 b0[KK], b1[KK];
    {
        const unsigned short* wp0 = Wc + (size_t)(wc * 32 + arow) * K + kseg * 8;
        const unsigned short* wp1 = wp0 + (size_t)16 * K;
        #pragma unroll
        for (int kk = 0; kk < KK; ++kk) {
            b0[kk] = *reinterpret_cast<const bf16x8*>(wp0 + kk * 32);
            b1[kk] = *reinterpret_cast<const bf16x8*>(wp1 + kk * 32);
        }
    }
    float bv0 = bias[wc * 32 + arow];
    float bv1 = bias[wc * 32 + 16 + arow];

    int g0 = blockIdx.x * (BM / 16) + wm * GW;

    bf16x8 a0[KK], a1[KK];

    #define LOADA(g, dst)                                                          \
    {                                                                              \
        int node = (g0 + (g)) * 16 + arow;                                         \
        int ncl = node < n ? node : 0;                                             \
        _Pragma("unroll")                                                          \
        for (int kk = 0; kk < KK; ++kk) {                                          \
            int k = kk * 32 + kseg * 8;                                            \
            const unsigned short* p = (k < DIN) ? (Ab + (size_t)ncl * DIN + k)     \
                                                : (Fb + (size_t)ncl * DIN + (k - DIN)); \
            dst[kk] = *reinterpret_cast<const bf16x8*>(p);                         \
        }                                                                          \
    }

    #define COMPUTE(g, ab)                                                         \
    {                                                                              \
        f32x4 acc0 = {0.f, 0.f, 0.f, 0.f}, acc1 = {0.f, 0.f, 0.f, 0.f};           \
        _Pragma("unroll")                                                          \
        for (int kk = 0; kk < KK; ++kk) {                                          \
            acc0 = __builtin_amdgcn_mfma_f32_16x16x32_bf16(ab[kk], b0[kk], acc0, 0, 0, 0); \
            acc1 = __builtin_amdgcn_mfma_f32_16x16x32_bf16(ab[kk], b1[kk], acc1, 0, 0, 0); \
        }                                                                          \
        int gbase = (g0 + (g)) * 16 + kseg * 4;                                    \
        _Pragma("unroll")                                                          \
        for (int r = 0; r < 4; ++r) {                                              \
            int gn = gbase + r;                                                    \
            if (gn < n) {                                                          \
                int col0 = wc * 32 + arow;                                         \
                float v0 = fmaxf(acc0[r] + bv0, 0.f);                              \
                float v1 = fmaxf(acc1[r] + bv1, 0.f);                              \
                out[(size_t)gn * outs + col0] = v0;                                \
                out[(size_t)gn * outs + col0 + 16] = v1;                           \
                if constexpr (WB) {                                                \
                    outb[(size_t)gn * DOUT + col0] = f2bf(v0);                     \
                    outb[(size_t)gn * DOUT + col0 + 16] = f2bf(v1);                \
                }                                                                  \
            }                                                                      \
        }                                                                          \
    }

    LOADA(0, a0);
    #pragma unroll
    for (int gp = 0; gp < GW; gp += 2) {
        LOADA(gp + 1, a1);
        COMPUTE(gp, a0);
        if (gp + 2 < GW) LOADA(gp + 2, a0);
        COMPUTE(gp + 1, a1);
    }
    #undef LOADA
    #undef COMPUTE
}

extern "C" void kernel_launch(void* const* d_in, const int* in_sizes, int n_in,
                              void* d_out, int out_size, void* d_ws, size_t ws_size,
                              hipStream_t stream) {
    const float* x   = (const float*)d_in[0];
    const int*   ei  = (const int*)d_in[1];
    const float* W1l = (const float*)d_in[2];
    const float* b1  = (const float*)d_in[3];
    const float* W1r = (const float*)d_in[4];
    const float* W2l = (const float*)d_in[5];
    const float* b2  = (const float*)d_in[6];
    const float* W2r = (const float*)d_in[7];
    const float* W3l = (const float*)d_in[8];
    const float* b3  = (const float*)d_in[9];
    const float* W3r = (const float*)d_in[10];
    float* out = (float*)d_out;

    const int* src = ei;
    const int* dst = ei + N_EDGES;

    int* wsi = (int*)d_ws;
    int*   cnt      = wsi;                    // NP
    int*   total    = wsi + NP;               // 64
    int*   row_ptr  = wsi + NP + 64;          // NP
    float* inv_deg  = (float*)(wsi + 2 * NP + 64);
    int*   edge_src = wsi + 3 * NP + 64;      // E
    int*   pos      = edge_src + N_EDGES;     // E
    unsigned short* Wc1 = (unsigned short*)(pos + N_EDGES);       // 128*256
    unsigned short* Wc2 = Wc1 + 128 * 256;                        // 64*256
    unsigned short* Wc3 = Wc2 + 64 * 256;                         // 128*128
    unsigned short* meanb = Wc3 + 128 * 128;                      // N*128 bf16
    unsigned short* xb  = meanb + (size_t)N_NODES * 128;          // N*128 bf16
    unsigned short* h1b = xb + (size_t)N_NODES * 128;             // N*128 bf16
    unsigned short* h2b = h1b + (size_t)N_NODES * 128;            // N*64  bf16

    // zero cnt + total with our own kernel (rocclr fillBuffer has ~40us fixed cost)
    zero_kernel<<<(NP + 64 + 255) / 256, 256, 0, stream>>>(cnt, NP + 64);

    // fused: count atomics + wcat builds + x->bf16
    prep_kernel<<<EB + WCB + CVB, 256, 0, stream>>>(dst, cnt, pos,
        W1l, W1r, W2l, W2r, W3l, W3r, Wc1, Wc2, Wc3, x, xb);

    assign_kernel<<<NP / 256, 256, 0, stream>>>(cnt, row_ptr, inv_deg, total, N_NODES);
    fill_kernel<<<EB, 256, 0, stream>>>(src, dst, row_ptr, pos, edge_src, N_EDGES);

    const int AGG_BLOCKS = (N_NODES + 3) / 4;
    const int GB64  = (N_NODES + 63) / 64;     // 782
    const int GB128 = (N_NODES + 127) / 128;   // 391

    // layer 1
    agg_kernel<128><<<AGG_BLOCKS, 256, 0, stream>>>(xb, row_ptr, cnt, edge_src, inv_deg, meanb, N_NODES);
    mfma_gemm_kernel<256, 128, true><<<GB64, 256, 0, stream>>>(meanb, xb, Wc1, b1, out, 320, h1b, N_NODES);

    // layer 2
    agg_kernel<128><<<AGG_BLOCKS, 256, 0, stream>>>(h1b, row_ptr, cnt, edge_src, inv_deg, meanb, N_NODES);
    mfma_gemm_kernel<256, 64, true><<<GB128, 256, 0, stream>>>(meanb, h1b, Wc2, b2, out + 128, 320, h2b, N_NODES);

    // layer 3
    agg_kernel<64><<<AGG_BLOCKS, 256, 0, stream>>>(h2b, row_ptr, cnt, edge_src, inv_deg, meanb, N_NODES);
    mfma_gemm_kernel<128, 128, false><<<GB64, 256, 0, stream>>>(meanb, h2b, Wc3, b3, out + 192, 320, nullptr, N_NODES);
}